// Round 5
// baseline (1140.160 us; speedup 1.0000x reference)
//
#include <hip/hip_runtime.h>
#include <hip/hip_bf16.h>
#include <math.h>

// Problem constants
#define Bz 4
#define Vz 2048
#define RA 40   // R*A = 5*8

typedef short bf16x8 __attribute__((ext_vector_type(8)));
typedef float f32x4 __attribute__((ext_vector_type(4)));

__device__ __forceinline__ unsigned fasu(float f){ union{float f;unsigned u;}x;x.f=f;return x.u; }
__device__ __forceinline__ float usaf(unsigned u){ union{unsigned u;float f;}x;x.u=u;return x.f; }

// fp32 -> bf16 RNE (weight split, done once per layer)
__device__ __forceinline__ unsigned short f2bf(float f) {
    unsigned u = fasu(f);
    unsigned r = u + 0x7FFF + ((u >> 16) & 1);
    return (unsigned short)(r >> 16);
}
__device__ __forceinline__ float bf2f(unsigned short h) { return usaf(((unsigned)h) << 16); }

__constant__ float NORM_MEAN_C[30] = {
    -3.7189561e-06f, 0.000286194f, 0.0020740835f, 6.5275993f, -0.0052857199f,
    10.554636f, 0.057773598f, 13.915789f, 0.060970016f, 16.840271f,
    0.0570364f, 19.415283f, 0.044104282f, 21.721455f, 0.11490919f,
    23.64683f, 0.099816084f, 25.365578f, 0.01769533f, 26.861437f,
    0.054662503f, 28.197876f, -0.0024771576f, 29.295244f, 0.039666731f,
    30.319246f, 0.0088442909f, 31.160933f, -0.026727753f, 31.874565f};
__constant__ float NORM_VAR_C[30] = {
    3.3091978e-06f, 0.00016750646f, 0.80988622f, 85135.219f, 1.5621265f,
    222580.2f, 8.812871f, 386912.78f, 10.180468f, 566622.44f,
    9.8600769f, 753158.06f, 7.8372045f, 942701.62f, 30.926426f,
    1117233.0f, 25.045353f, 1285543.9f, 6.3646226f, 1441639.1f,
    12.326629f, 1588653.4f, 6.9686499f, 1714707.9f, 10.755516f,
    1836677.8f, 8.416419f, 1940088.8f, 10.344138f, 2029969.6f};

__device__ __forceinline__ float elu_f(float x) {
    return x > 0.f ? x : expm1f(x);
}

// x0[b,v,c] = (signal - mean[c]) * rsqrt(var[c])
__global__ void norm_kernel(const float* __restrict__ sig, float* __restrict__ x0) {
    int e = blockIdx.x * 256 + threadIdx.x;
    if (e >= Bz * Vz * 30) return;
    int c = e % 30;
    x0[e] = (sig[e] - NORM_MEAN_C[c]) * rsqrtf(NORM_VAR_C[c]);
}

// Weight expand (no rotation; rotations live in M). Split-bf16, fragment-linear:
// per (kb,plane): off = (n>>4)*512 + (kk>>3)*128 + (n&15)*8 + (kk&7)
template <int CROW, int T, int KB>
__global__ void expand_wt(const float* __restrict__ kern, unsigned short* __restrict__ wt) {
    int e = blockIdx.x * 256 + threadIdx.x;
    if (e >= KB * T * 32) return;
    int kb = e / (T * 32);
    int rem = e % (T * 32);
    int n = rem >> 5, kk = rem & 31;
    int ra, c;
    if (CROW == 128) { ra = kb >> 2; c = (kb & 3) * 32 + kk; }
    else             { ra = kb;      c = kk; }
    float v = (c < CROW) ? kern[((size_t)(ra * T + n)) * CROW + c] : 0.f;
    unsigned short hi = f2bf(v);
    unsigned short lo = f2bf(v - bf2f(hi));
    size_t off = ((size_t)kb * 2) * T * 32 + (n >> 4) * 512 + (kk >> 3) * 128 + (n & 15) * 8 + (kk & 7);
    wt[off] = hi;
    wt[off + (size_t)T * 32] = lo;
}

// Fused conv GEMM, 16x16x32, BM=64, NW column-waves (64*NW thr), BN=64*NW=T.
// R5 change: CHUNK-level LDS double-buffering. R3 had one barrier per 8-ap
// group (20/kernel); each barrier = compiler-forced vmcnt(0)+lgkmcnt(0) drain,
// and MfmaUtil(59)+VALUBusy(24)=83% left ~17% drained-stall. Now a chunk = 4
// group-tiles (one full r, 32KB LDS per plane-pair, 64KB total dbuf, still 2
// blocks/CU at ~66KB), builds for the NEXT chunk are spread across the 32
// ap-slots of the current chunk (per-slot task density same as R3: slot 0-1
// gather issue + idx prefetch, then interp chunks, then split halves), and
// there is ONE barrier per chunk: 5 per kernel instead of 20, with a
// 1536-MFMA barrier-free run per wave so the 2 resident blocks desynchronize
// and hide each other's B-load/gather latency. Layer 0 (CROW=30): whole I
// built in prologue, ZERO in-loop barriers.
// R4 lesson kept: arch VGPR must stay <=128 (pow2 bucket + 64 AGPR separate;
// 132 arch halved residency). Build state is scoped per 8-slot window, so the
// transient register footprint matches R3 (~112).
// Epilogue: elu+bias, AMP argmax over 8 rotations, BN, write [v][T].
template <int CROW, int T, int KB, int NW, bool FUSE>
__global__ __launch_bounds__(64 * NW) void conv_k(const float* __restrict__ x,
                                              const int* __restrict__ bc_idx,
                                              const float* __restrict__ bc_w,
                                              const unsigned short* __restrict__ wt,
                                              const float* __restrict__ bias,
                                              const float* __restrict__ g,
                                              const float* __restrict__ be,
                                              float* __restrict__ xout) {
    constexpr int CB = (CROW == 128) ? 4 : 1;   // c-blocks per ra
    constexpr int G = KB / 8;                   // (r,cblk) groups
    constexpr int CHUNK_G = (CROW == 128) ? 4 : G;   // groups per chunk
    constexpr int NCH = G / CHUNK_G;            // chunks (5 for 128; 1 for 30)
    constexpr int NBUF = (NCH > 1) ? 2 : 1;
    constexpr int CPT = 32 / NW;                // k-elements built per thread
    constexpr int NI = CPT / 4;                 // interp chunks (4 elems each)
    constexpr int NSW = CPT / 8;                // split+write halves (8 elems)
    __shared__ unsigned short Ih[NBUF][CHUNK_G * 2048], Il[NBUF][CHUNK_G * 2048];
    __shared__ float normp[64][NW];
    __shared__ int bo[8];
    const int tid = threadIdx.x;
    const int wid = tid >> 6, lane = tid & 63;
    const int fr = lane & 15, fq = lane >> 4;
    const int fro = fr & 7, frv = fr & 8;
    const int wn = wid * 64;                      // column-wave offset
    const int m0 = blockIdx.y * 64;
    const int b = m0 >> 14;                       // batch
    const float* xb_ = x + (size_t)b * Vz * CROW;
    const int* idxb = bc_idx + (size_t)b * Vz * RA * 3;
    const float* wb = bc_w + (size_t)b * Vz * RA * 3;

    // I-build mapping: NW threads per I row; thread covers CPT k's
    const int rloc = tid / NW;                    // 0..63  (v = rloc>>3, a = rloc&7)
    const int cidx = tid % NW;                    // which CPT chunk
    const int aI = rloc & 7;
    const int vglob_b = ((m0 & 16383) >> 3) + (rloc >> 3);
    const int offA = (rloc >> 4) * 512 + (cidx * CPT / 8) * 128 + (rloc & 15) * 8;
    // A-fragment base (lane-const); per a': addr = tbase + ibase + mi*512 + rot*8
    const int ibase = fq * 128 + frv * 8;
    // B-fragment base n-block
    const int nbase = wn >> 4;

    f32x4 acc[4][4] = {};

    auto split_write_half = [&](const float* vv, int h, int buf, int tbase) {
        unsigned hiw[4], low_[4];
#pragma unroll
        for (int p = 0; p < 4; ++p) {
            float v0 = vv[h * 8 + 2 * p], v1 = vv[h * 8 + 2 * p + 1];
            unsigned u0 = fasu(v0), u1 = fasu(v1);
            unsigned h0 = u0 & 0xFFFF0000u, h1 = u1 & 0xFFFF0000u;
            float l0 = v0 - usaf(h0), l1 = v1 - usaf(h1);
            hiw[p] = (u0 >> 16) | h1;
            low_[p] = (fasu(l0) >> 16) | (fasu(l1) & 0xFFFF0000u);
        }
        *(uint4*)&Ih[buf][tbase + offA + h * 128] = make_uint4(hiw[0], hiw[1], hiw[2], hiw[3]);
        *(uint4*)&Il[buf][tbase + offA + h * 128] = make_uint4(low_[0], low_[1], low_[2], low_[3]);
    };

    // full build of one group tile (prologue only; serial)
    auto build_full = [&](int rb, int cb, int buf, int tbase) {
        const int gi_ = (vglob_b * RA + rb * 8 + aI) * 3;
        int a0 = idxb[gi_], a1 = idxb[gi_ + 1], a2 = idxb[gi_ + 2];
        float b0_ = wb[gi_], b1_ = wb[gi_ + 1], b2_ = wb[gi_ + 2];
        float vv[CPT];
        const int cs0 = cb * 32 + cidx * CPT;
        if (CROW == 128) {
            const float4* q0 = (const float4*)(xb_ + (size_t)a0 * CROW + cs0);
            const float4* q1 = (const float4*)(xb_ + (size_t)a1 * CROW + cs0);
            const float4* q2 = (const float4*)(xb_ + (size_t)a2 * CROW + cs0);
#pragma unroll
            for (int qq = 0; qq < NI; ++qq) {
                float4 a4 = q0[qq], b4 = q1[qq], c4 = q2[qq];
                vv[qq * 4 + 0] = b0_ * a4.x + b1_ * b4.x + b2_ * c4.x;
                vv[qq * 4 + 1] = b0_ * a4.y + b1_ * b4.y + b2_ * c4.y;
                vv[qq * 4 + 2] = b0_ * a4.z + b1_ * b4.z + b2_ * c4.z;
                vv[qq * 4 + 3] = b0_ * a4.w + b1_ * b4.w + b2_ * c4.w;
            }
        } else {
            const float* q0 = xb_ + (size_t)a0 * CROW;
            const float* q1 = xb_ + (size_t)a1 * CROW;
            const float* q2 = xb_ + (size_t)a2 * CROW;
#pragma unroll
            for (int j = 0; j < CPT; ++j) {
                int c = cs0 + j;
                vv[j] = (c < CROW) ? (b0_ * q0[c] + b1_ * q1[c] + b2_ * q2[c]) : 0.f;
            }
        }
#pragma unroll
        for (int h = 0; h < NSW; ++h) split_write_half(vv, h, buf, tbase);
    };

    // ---- prologue: build ALL CHUNK_G tiles of chunk 0; preload idx/w for
    //      the first build group (bg = CHUNK_G) ----
    int i_n0 = 0, i_n1 = 0, i_n2 = 0; float w_n0 = 0.f, w_n1 = 0.f, w_n2 = 0.f;
#pragma unroll
    for (int j = 0; j < CHUNK_G; ++j)
        build_full(j / CB, j % CB, 0, j * 2048);
    if (NCH > 1) {
        const int rn0 = CHUNK_G / CB;             // = 1 for CROW=128
        const int gi2 = (vglob_b * RA + rn0 * 8 + aI) * 3;
        i_n0 = idxb[gi2]; i_n1 = idxb[gi2 + 1]; i_n2 = idxb[gi2 + 2];
        w_n0 = wb[gi2];   w_n1 = wb[gi2 + 1];   w_n2 = wb[gi2 + 2];
    }
    __syncthreads();

    int cur = 0;
    for (int ch = 0; ch < NCH; ++ch) {
        const bool hb = (ch + 1 < NCH);           // builds active this chunk
#pragma unroll
        for (int gi = 0; gi < CHUNK_G; ++gi) {
            // window state for building bg = (ch+1)*CHUNK_G + gi
            const int ni0 = i_n0, ni1 = i_n1, ni2 = i_n2;
            const float nw0 = w_n0, nw1 = w_n1, nw2 = w_n2;
            float4 qr0[NI], qr1[NI], qr2[NI];
            float vv[CPT];
            const int cs_b = gi * 32 + cidx * CPT;    // bg%CB == gi (CHUNK_G==CB)
            const int tbase = gi * 2048;
#pragma unroll
            for (int ap = 0; ap < 8; ++ap) {
                // ---- B fragment loads (L2-resident wt) ----
                const int kb = (CROW == 128) ? ((ch * 8 + ap) * 4 + gi) : (gi * 8 + ap);
                const unsigned short* bb = wt + ((size_t)kb * 2) * (T * 32) +
                                           (size_t)nbase * 512 + lane * 8;
                bf16x8 bh[4], bl[4];
#pragma unroll
                for (int nj = 0; nj < 4; ++nj) {
                    bh[nj] = *(const bf16x8*)(bb + nj * 512);
                    bl[nj] = *(const bf16x8*)(bb + (size_t)T * 32 + nj * 512);
                }
                // ---- A fragments from LDS (rotation folded into addr) ----
                const int rot = (ap + fro) & 7;
                bf16x8 ah[4], al[4];
#pragma unroll
                for (int mi = 0; mi < 4; ++mi) {
                    const int ad = tbase + ibase + mi * 512 + rot * 8;
                    ah[mi] = *(const bf16x8*)&Ih[cur][ad];
                    al[mi] = *(const bf16x8*)&Il[cur][ad];
                }
                __builtin_amdgcn_s_setprio(1);
#pragma unroll
                for (int mi = 0; mi < 4; ++mi)
#pragma unroll
                    for (int nj = 0; nj < 4; ++nj) {
                        acc[mi][nj] = __builtin_amdgcn_mfma_f32_16x16x32_bf16(ah[mi], bh[nj], acc[mi][nj], 0, 0, 0);
                        acc[mi][nj] = __builtin_amdgcn_mfma_f32_16x16x32_bf16(ah[mi], bl[nj], acc[mi][nj], 0, 0, 0);
                        acc[mi][nj] = __builtin_amdgcn_mfma_f32_16x16x32_bf16(al[mi], bh[nj], acc[mi][nj], 0, 0, 0);
                    }
                __builtin_amdgcn_s_setprio(0);
                // ---- build task for next-chunk tile gi (CROW=128 only) ----
                if constexpr (NCH > 1) {
                    if (hb) {
                        if (ap == 0) {
                            const float4* q0 = (const float4*)(xb_ + (size_t)ni0 * CROW + cs_b);
                            const float4* q1 = (const float4*)(xb_ + (size_t)ni1 * CROW + cs_b);
#pragma unroll
                            for (int qq = 0; qq < NI; ++qq) { qr0[qq] = q0[qq]; qr1[qq] = q1[qq]; }
                        } else if (ap == 1) {
                            const float4* q2 = (const float4*)(xb_ + (size_t)ni2 * CROW + cs_b);
#pragma unroll
                            for (int qq = 0; qq < NI; ++qq) qr2[qq] = q2[qq];
                            const int bg1 = (ch + 1) * CHUNK_G + gi + 1;
                            if (bg1 < G) {
                                const int rn = bg1 / CB;
                                const int gi2 = (vglob_b * RA + rn * 8 + aI) * 3;
                                i_n0 = idxb[gi2]; i_n1 = idxb[gi2 + 1]; i_n2 = idxb[gi2 + 2];
                                w_n0 = wb[gi2];   w_n1 = wb[gi2 + 1];   w_n2 = wb[gi2 + 2];
                            }
                        } else if (ap - 2 < NI) {
                            const int t_ = ap - 2;
                            float4 a4 = qr0[t_], b4 = qr1[t_], c4 = qr2[t_];
                            vv[t_ * 4 + 0] = nw0 * a4.x + nw1 * b4.x + nw2 * c4.x;
                            vv[t_ * 4 + 1] = nw0 * a4.y + nw1 * b4.y + nw2 * c4.y;
                            vv[t_ * 4 + 2] = nw0 * a4.z + nw1 * b4.z + nw2 * c4.z;
                            vv[t_ * 4 + 3] = nw0 * a4.w + nw1 * b4.w + nw2 * c4.w;
                        } else if (ap - 2 - NI < NSW) {
                            split_write_half(vv, ap - 2 - NI, cur ^ 1, tbase);
                        }
                    }
                }
            }
        }
        if (NBUF > 1) {
            __syncthreads();
            cur ^= 1;
        }
    }

    if (FUSE) {
        // elu + bias, per-row squared norms, argmax over 8 rotations, BN, write
        float ss[4][4];
#pragma unroll
        for (int mi = 0; mi < 4; ++mi)
#pragma unroll
            for (int r = 0; r < 4; ++r) ss[mi][r] = 0.f;
#pragma unroll
        for (int mi = 0; mi < 4; ++mi)
#pragma unroll
            for (int nj = 0; nj < 4; ++nj)
#pragma unroll
                for (int r = 0; r < 4; ++r) {
                    float val = elu_f(acc[mi][nj][r] + bias[wn + nj * 16 + fr]);
                    acc[mi][nj][r] = val;
                    ss[mi][r] += val * val;
                }
#pragma unroll
        for (int mi = 0; mi < 4; ++mi)
#pragma unroll
            for (int r = 0; r < 4; ++r) {
                float s = ss[mi][r];
                s += __shfl_xor(s, 1); s += __shfl_xor(s, 2);
                s += __shfl_xor(s, 4); s += __shfl_xor(s, 8);
                if (fr == 0) normp[mi * 16 + fq * 4 + r][wid] = s;
            }
        __syncthreads();
        if (tid < 8) {
            float best = -1.f; int bsel = 0;
#pragma unroll
            for (int oo = 0; oo < 8; ++oo) {
                float tot = 0.f;
#pragma unroll
                for (int wq = 0; wq < NW; ++wq) tot += normp[tid * 8 + oo][wq];
                if (tot > best) { best = tot; bsel = oo; }   // first max wins
            }
            bo[tid] = bsel;
        }
        __syncthreads();
        const float rsbn = rsqrtf(1.001f);
#pragma unroll
        for (int mi = 0; mi < 4; ++mi)
#pragma unroll
            for (int r = 0; r < 4; ++r) {
                int row = mi * 16 + fq * 4 + r;
                if ((row & 7) == bo[row >> 3]) {
                    int vg = (m0 >> 3) + (row >> 3);   // global vertex 0..8191
#pragma unroll
                    for (int nj = 0; nj < 4; ++nj) {
                        int t = wn + nj * 16 + fr;
                        xout[(size_t)vg * T + t] = acc[mi][nj][r] * g[t] * rsbn + be[t];
                    }
                }
            }
    }
}

// Global max pool stage 1. x: [B][V][256] -> partial [B*32][256]
__global__ void pool1(const float* __restrict__ x, float* __restrict__ partial) {
    int b = blockIdx.x >> 5, ch = blockIdx.x & 31, t = threadIdx.x;
    float m = -INFINITY;
    for (int i = 0; i < 64; ++i) {
        int v = ch * 64 + i;
        m = fmaxf(m, x[((size_t)b * Vz + v) * 256 + t]);
    }
    partial[(size_t)blockIdx.x * 256 + t] = m;
}

// Fused head: finish max-pool + 3-layer MLP. One block per batch.
__global__ __launch_bounds__(256) void head_k(const float* __restrict__ partial,
                                              const float* __restrict__ w1, const float* __restrict__ c1,
                                              const float* __restrict__ w2, const float* __restrict__ c2,
                                              const float* __restrict__ w3, const float* __restrict__ c3,
                                              float* __restrict__ outp) {
    __shared__ float p[256], h1s[512], h2s[256];
    const int b = blockIdx.x, tid = threadIdx.x;
    float m = -INFINITY;
#pragma unroll
    for (int ch = 0; ch < 32; ++ch)
        m = fmaxf(m, partial[((size_t)b * 32 + ch) * 256 + tid]);
    p[tid] = m;
    __syncthreads();
#pragma unroll
    for (int rep = 0; rep < 2; ++rep) {
        int n = rep * 256 + tid;
        float s = c1[n];
        for (int k = 0; k < 256; ++k) s += p[k] * w1[k * 512 + n];
        h1s[n] = elu_f(s);
    }
    __syncthreads();
    {
        float s = c2[tid];
        for (int k = 0; k < 512; ++k) s += h1s[k] * w2[k * 256 + tid];
        h2s[tid] = elu_f(s);
    }
    __syncthreads();
    if (tid < 40) {
        float s = c3[tid];
        for (int k = 0; k < 256; ++k) s += h2s[k] * w3[k * 40 + tid];
        outp[b * 40 + tid] = s;
    }
}

extern "C" void kernel_launch(void* const* d_in, const int* in_sizes, int n_in,
                              void* d_out, int out_size, void* d_ws, size_t ws_size,
                              hipStream_t stream) {
    const float* signal = (const float*)d_in[0];
    const int* bc_idx = (const int*)d_in[1];
    const float* bc_w = (const float*)d_in[2];
    const float* k0 = (const float*)d_in[3];
    const float* b0 = (const float*)d_in[4];
    const float* g0 = (const float*)d_in[5];
    const float* be0 = (const float*)d_in[6];
    const float* k1 = (const float*)d_in[7];
    const float* b1 = (const float*)d_in[8];
    const float* g1 = (const float*)d_in[9];
    const float* be1 = (const float*)d_in[10];
    const float* k2 = (const float*)d_in[11];
    const float* b2 = (const float*)d_in[12];
    const float* g2 = (const float*)d_in[13];
    const float* be2 = (const float*)d_in[14];
    const float* w1 = (const float*)d_in[15];
    const float* c1 = (const float*)d_in[16];
    const float* w2 = (const float*)d_in[17];
    const float* c2 = (const float*)d_in[18];
    const float* w3 = (const float*)d_in[19];
    const float* c3 = (const float*)d_in[20];
    float* outp = (float*)d_out;

    // Workspace: xa 8.4 + xb 8.4 + small(128KB) + wt 5.24 MB ~= 22.2 MB
    float* ws = (float*)d_ws;
    float* xa = ws;                                    // [8192][<=256] f32
    float* xb = xa + (size_t)8192 * 256;
    float* small = xb + (size_t)8192 * 256;
    float* partial = small;                            // 4*32*256 = 32768 f32
    unsigned short* wt = (unsigned short*)(small + 32768);  // max 160*2*256*32 u16 = 5.24 MB

    // 1. input normalization -> xa [8192][30]
    norm_kernel<<<(Bz * Vz * 30 + 255) / 256, 256, 0, stream>>>(signal, xa);

    // ---- layer 0: CROW=30 (KB=40), T=128, NW=2 (128 thr, BM=64), fused AMP ----
    expand_wt<30, 128, 40><<<(40 * 128 * 32 + 255) / 256, 256, 0, stream>>>(k0, wt);
    conv_k<30, 128, 40, 2, true><<<dim3(1, 1024), 128, 0, stream>>>(
        xa, bc_idx, bc_w, wt, b0, g0, be0, xb);

    // ---- layer 1: CROW=128 (KB=160), T=128, NW=2 (128 thr, BM=64), fused AMP ----
    expand_wt<128, 128, 160><<<(160 * 128 * 32 + 255) / 256, 256, 0, stream>>>(k1, wt);
    conv_k<128, 128, 160, 2, true><<<dim3(1, 1024), 128, 0, stream>>>(
        xb, bc_idx, bc_w, wt, b1, g1, be1, xa);

    // ---- layer 2: CROW=128 (KB=160), T=256, NW=4 (256 thr, BM=64), fused AMP ----
    expand_wt<128, 256, 160><<<(160 * 256 * 32 + 255) / 256, 256, 0, stream>>>(k2, wt);
    conv_k<128, 256, 160, 4, true><<<dim3(1, 1024), 256, 0, stream>>>(
        xa, bc_idx, bc_w, wt, b2, g2, be2, xb);

    // ---- global max pool + fused MLP head ----
    pool1<<<Bz * 32, 256, 0, stream>>>(xb, partial);
    head_k<<<Bz, 256, 0, stream>>>(partial, w1, c1, w2, c2, w3, c3, outp);
}

// Round 6
// 785.223 us; speedup vs baseline: 1.4520x; 1.4520x over previous
//
#include <hip/hip_runtime.h>
#include <hip/hip_bf16.h>
#include <math.h>

// Problem constants
#define Bz 4
#define Vz 2048
#define RA 40   // R*A = 5*8

typedef short bf16x8 __attribute__((ext_vector_type(8)));
typedef float f32x4 __attribute__((ext_vector_type(4)));

__device__ __forceinline__ unsigned fasu(float f){ union{float f;unsigned u;}x;x.f=f;return x.u; }
__device__ __forceinline__ float usaf(unsigned u){ union{unsigned u;float f;}x;x.u=u;return x.f; }

// fp32 -> bf16 RNE (weight split, done once per layer)
__device__ __forceinline__ unsigned short f2bf(float f) {
    unsigned u = fasu(f);
    unsigned r = u + 0x7FFF + ((u >> 16) & 1);
    return (unsigned short)(r >> 16);
}
__device__ __forceinline__ float bf2f(unsigned short h) { return usaf(((unsigned)h) << 16); }

__constant__ float NORM_MEAN_C[30] = {
    -3.7189561e-06f, 0.000286194f, 0.0020740835f, 6.5275993f, -0.0052857199f,
    10.554636f, 0.057773598f, 13.915789f, 0.060970016f, 16.840271f,
    0.0570364f, 19.415283f, 0.044104282f, 21.721455f, 0.11490919f,
    23.64683f, 0.099816084f, 25.365578f, 0.01769533f, 26.861437f,
    0.054662503f, 28.197876f, -0.0024771576f, 29.295244f, 0.039666731f,
    30.319246f, 0.0088442909f, 31.160933f, -0.026727753f, 31.874565f};
__constant__ float NORM_VAR_C[30] = {
    3.3091978e-06f, 0.00016750646f, 0.80988622f, 85135.219f, 1.5621265f,
    222580.2f, 8.812871f, 386912.78f, 10.180468f, 566622.44f,
    9.8600769f, 753158.06f, 7.8372045f, 942701.62f, 30.926426f,
    1117233.0f, 25.045353f, 1285543.9f, 6.3646226f, 1441639.1f,
    12.326629f, 1588653.4f, 6.9686499f, 1714707.9f, 10.755516f,
    1836677.8f, 8.416419f, 1940088.8f, 10.344138f, 2029969.6f};

__device__ __forceinline__ float elu_f(float x) {
    return x > 0.f ? x : expm1f(x);
}

// order-preserving float->uint map (uint max == float max, bit-exact)
__device__ __forceinline__ unsigned encf(float f) {
    unsigned u = fasu(f);
    return (f < 0.f) ? ~u : (u | 0x80000000u);
}
__device__ __forceinline__ float decf(unsigned u) {
    return (u & 0x80000000u) ? usaf(u & 0x7FFFFFFFu) : usaf(~u);
}

// Weight expand body (no rotation; rotations live in M). Split-bf16,
// fragment-linear: off = (n>>4)*512 + (kk>>3)*128 + (n&15)*8 + (kk&7)
template <int CROW, int T, int KB>
__device__ __forceinline__ void expand_body(int e, const float* __restrict__ kern,
                                            unsigned short* __restrict__ wt) {
    int kb = e / (T * 32);
    int rem = e % (T * 32);
    int n = rem >> 5, kk = rem & 31;
    int ra, c;
    if (CROW == 128) { ra = kb >> 2; c = (kb & 3) * 32 + kk; }
    else             { ra = kb;      c = kk; }
    float v = (c < CROW) ? kern[((size_t)(ra * T + n)) * CROW + c] : 0.f;
    unsigned short hi = f2bf(v);
    unsigned short lo = f2bf(v - bf2f(hi));
    size_t off = ((size_t)kb * 2) * T * 32 + (n >> 4) * 512 + (kk >> 3) * 128 + (n & 15) * 8 + (kk & 7);
    wt[off] = hi;
    wt[off + (size_t)T * 32] = lo;
}

// One prep dispatch replaces: norm_kernel + 3x expand_wt + pool-buffer zero.
// All are input-only dependent; region-dispatch on blockIdx.x.
// ranges: [0,960) norm | [960,1600) e0 | [1600,4160) e1 | [4160,9280) e2 |
//         [9280,9284) zero gpool
__global__ void prep_k(const float* __restrict__ sig, float* __restrict__ x0,
                       const float* __restrict__ k0, unsigned short* __restrict__ wt0,
                       const float* __restrict__ k1, unsigned short* __restrict__ wt1,
                       const float* __restrict__ k2, unsigned short* __restrict__ wt2,
                       unsigned* __restrict__ gpool) {
    const int bid = blockIdx.x, tid = threadIdx.x;
    if (bid < 960) {
        int e = bid * 256 + tid;
        if (e < Bz * Vz * 30) {
            int c = e % 30;
            x0[e] = (sig[e] - NORM_MEAN_C[c]) * rsqrtf(NORM_VAR_C[c]);
        }
    } else if (bid < 1600) {
        int e = (bid - 960) * 256 + tid;
        if (e < 40 * 128 * 32) expand_body<30, 128, 40>(e, k0, wt0);
    } else if (bid < 4160) {
        int e = (bid - 1600) * 256 + tid;
        if (e < 160 * 128 * 32) expand_body<128, 128, 160>(e, k1, wt1);
    } else if (bid < 9280) {
        int e = (bid - 4160) * 256 + tid;
        if (e < 160 * 256 * 32) expand_body<128, 256, 160>(e, k2, wt2);
    } else {
        int e = (bid - 9280) * 256 + tid;
        if (e < Bz * 256) gpool[e] = 0u;
    }
}

// Fused conv GEMM, 16x16x32, BM=64, NW column-waves (64*NW thr), BN=64*NW=T.
// R3 schedule (proven best): per 8-ap group, x-gathers for g+1 issued up
// front (held in regs), idx/w prefetch for g+2, I-build VALU tasks
// interleaved between the 8 MFMA clusters, s_setprio around each cluster,
// ONE barrier per group. Lessons pinned: arch VGPR must stay <=128 (pow2
// bucket + 64 AGPR separate; R4's 132 and R5's restructure both halved
// residency and regressed).
// R6: POOL variant (layer 2) fuses GlobalMaxPool into the epilogue: after
// BN, order-preserving-uint atomicMax into LDS[256], then one global
// atomicMax per channel. Layer-2 activation is never materialized (kills
// the 8MB store + pool1's 16MB round trip).
// Epilogue: elu+bias, AMP argmax over 8 rotations, BN, then write or pool.
template <int CROW, int T, int KB, int NW, bool FUSE, bool POOL>
__global__ __launch_bounds__(64 * NW) void conv_k(const float* __restrict__ x,
                                              const int* __restrict__ bc_idx,
                                              const float* __restrict__ bc_w,
                                              const unsigned short* __restrict__ wt,
                                              const float* __restrict__ bias,
                                              const float* __restrict__ g,
                                              const float* __restrict__ be,
                                              float* __restrict__ xout) {
    constexpr int CB = (CROW == 128) ? 4 : 1;   // c-blocks per ra
    constexpr int G = KB / 8;                   // (r,cblk) groups
    constexpr int CPT = 32 / NW;                // k-elements built per thread
    constexpr int NI = CPT / 4;                 // interp chunks (4 elems each)
    constexpr int NSW = CPT / 8;                // split+write halves (8 elems)
    __shared__ unsigned short Ih[2][2048], Il[2][2048];
    __shared__ float normp[64][NW];
    __shared__ int bo[8];
    __shared__ unsigned poolmax[64 * NW];
    const int tid = threadIdx.x;
    const int wid = tid >> 6, lane = tid & 63;
    const int fr = lane & 15, fq = lane >> 4;
    const int fro = fr & 7, frv = fr & 8;
    const int wn = wid * 64;                      // column-wave offset
    const int m0 = blockIdx.y * 64;
    const int b = m0 >> 14;                       // batch
    const float* xb_ = x + (size_t)b * Vz * CROW;
    const int* idxb = bc_idx + (size_t)b * Vz * RA * 3;
    const float* wb = bc_w + (size_t)b * Vz * RA * 3;

    // I-build mapping: NW threads per I row; thread covers CPT k's
    const int rloc = tid / NW;                    // 0..63  (v = rloc>>3, a = rloc&7)
    const int cidx = tid % NW;                    // which CPT chunk
    const int aI = rloc & 7;
    const int vglob_b = ((m0 & 16383) >> 3) + (rloc >> 3);
    const int offA = (rloc >> 4) * 512 + (cidx * CPT / 8) * 128 + (rloc & 15) * 8;
    // A-fragment base (lane-const); per a': addr = ibase + mi*512 + rot*8
    const int ibase = fq * 128 + frv * 8;
    // B-fragment base n-block
    const int nbase = wn >> 4;

    f32x4 acc[4][4] = {};

    auto split_write_half = [&](const float* vv, int h, int buf) {
        unsigned hiw[4], low_[4];
#pragma unroll
        for (int p = 0; p < 4; ++p) {
            float v0 = vv[h * 8 + 2 * p], v1 = vv[h * 8 + 2 * p + 1];
            unsigned u0 = fasu(v0), u1 = fasu(v1);
            unsigned h0 = u0 & 0xFFFF0000u, h1 = u1 & 0xFFFF0000u;
            float l0 = v0 - usaf(h0), l1 = v1 - usaf(h1);
            hiw[p] = (u0 >> 16) | h1;
            low_[p] = (fasu(l0) >> 16) | (fasu(l1) & 0xFFFF0000u);
        }
        *(uint4*)&Ih[buf][offA + h * 128] = make_uint4(hiw[0], hiw[1], hiw[2], hiw[3]);
        *(uint4*)&Il[buf][offA + h * 128] = make_uint4(low_[0], low_[1], low_[2], low_[3]);
    };

    // ---- prologue: build I for group 0; prefetch idx/w for group 1 ----
    int i_n0 = 0, i_n1 = 0, i_n2 = 0; float w_n0 = 0.f, w_n1 = 0.f, w_n2 = 0.f;
    {
        const int gi = (vglob_b * RA + aI) * 3;   // g=0 -> r=0
        int a0 = idxb[gi], a1 = idxb[gi + 1], a2 = idxb[gi + 2];
        float b0_ = wb[gi], b1_ = wb[gi + 1], b2_ = wb[gi + 2];
        float vv[CPT];
        const int cs0 = cidx * CPT;               // g=0 -> cb=0
        if (CROW == 128) {
            const float4* q0 = (const float4*)(xb_ + (size_t)a0 * CROW + cs0);
            const float4* q1 = (const float4*)(xb_ + (size_t)a1 * CROW + cs0);
            const float4* q2 = (const float4*)(xb_ + (size_t)a2 * CROW + cs0);
#pragma unroll
            for (int qq = 0; qq < CPT / 4; ++qq) {
                float4 a4 = q0[qq], b4 = q1[qq], c4 = q2[qq];
                vv[qq * 4 + 0] = b0_ * a4.x + b1_ * b4.x + b2_ * c4.x;
                vv[qq * 4 + 1] = b0_ * a4.y + b1_ * b4.y + b2_ * c4.y;
                vv[qq * 4 + 2] = b0_ * a4.z + b1_ * b4.z + b2_ * c4.z;
                vv[qq * 4 + 3] = b0_ * a4.w + b1_ * b4.w + b2_ * c4.w;
            }
        } else {
            const float* q0 = xb_ + (size_t)a0 * CROW;
            const float* q1 = xb_ + (size_t)a1 * CROW;
            const float* q2 = xb_ + (size_t)a2 * CROW;
#pragma unroll
            for (int j = 0; j < CPT; ++j) {
                int c = cs0 + j;
                vv[j] = (c < CROW) ? (b0_ * q0[c] + b1_ * q1[c] + b2_ * q2[c]) : 0.f;
            }
        }
#pragma unroll
        for (int h = 0; h < NSW; ++h) split_write_half(vv, h, 0);
        if (G > 1) {
            const int rn = 1 / CB;
            const int gi2 = (vglob_b * RA + rn * 8 + aI) * 3;
            i_n0 = idxb[gi2]; i_n1 = idxb[gi2 + 1]; i_n2 = idxb[gi2 + 2];
            w_n0 = wb[gi2];   w_n1 = wb[gi2 + 1];   w_n2 = wb[gi2 + 2];
        }
    }
    __syncthreads();

    for (int gidx = 0; gidx < G; ++gidx) {
        const bool hn = (gidx + 1 < G);
        // save next-group idx/w before the g+2 prefetch overwrites them
        const int ni0 = i_n0, ni1 = i_n1, ni2 = i_n2;
        const float nw0 = w_n0, nw1 = w_n1, nw2 = w_n2;
        const int cs_n = ((gidx + 1) % CB) * 32 + cidx * CPT;

        // ---- 1. issue x-gathers for group g+1 (held in regs through MFMAs) ----
        float4 qr0[CPT / 4], qr1[CPT / 4], qr2[CPT / 4];
        float gq0[CPT], gq1[CPT], gq2[CPT];
        if (hn) {
            if (CROW == 128) {
                const float4* q0 = (const float4*)(xb_ + (size_t)ni0 * CROW + cs_n);
                const float4* q1 = (const float4*)(xb_ + (size_t)ni1 * CROW + cs_n);
                const float4* q2 = (const float4*)(xb_ + (size_t)ni2 * CROW + cs_n);
#pragma unroll
                for (int qq = 0; qq < CPT / 4; ++qq) { qr0[qq] = q0[qq]; qr1[qq] = q1[qq]; qr2[qq] = q2[qq]; }
            } else {
                const float* q0 = xb_ + (size_t)ni0 * CROW;
                const float* q1 = xb_ + (size_t)ni1 * CROW;
                const float* q2 = xb_ + (size_t)ni2 * CROW;
#pragma unroll
                for (int j = 0; j < CPT; ++j) {
                    int c = cs_n + j;
                    bool ok = (c < CROW);
                    gq0[j] = ok ? q0[c] : 0.f;
                    gq1[j] = ok ? q1[c] : 0.f;
                    gq2[j] = ok ? q2[c] : 0.f;
                }
            }
        }
        // ---- 2. prefetch idx/w for group g+2 ----
        if (gidx + 2 < G) {
            const int rn = (gidx + 2) / CB;
            const int gi = (vglob_b * RA + rn * 8 + aI) * 3;
            i_n0 = idxb[gi]; i_n1 = idxb[gi + 1]; i_n2 = idxb[gi + 2];
            w_n0 = wb[gi];   w_n1 = wb[gi + 1];   w_n2 = wb[gi + 2];
        }

        // ---- 3. 8 MFMA steps with I-build tasks interleaved between clusters.
        const int r8 = (gidx / CB) * 8;
        const int cbg = gidx % CB;
        const int ibuf = gidx & 1;
        float vv[CPT];
#pragma unroll
        for (int ap = 0; ap < 8; ++ap) {
            const int kb = (CROW == 128) ? ((r8 + ap) * 4 + cbg) : (r8 + ap);
            const unsigned short* bb = wt + ((size_t)kb * 2) * (T * 32) +
                                       (size_t)nbase * 512 + lane * 8;
            bf16x8 bh[4], bl[4];
#pragma unroll
            for (int nj = 0; nj < 4; ++nj) {
                bh[nj] = *(const bf16x8*)(bb + nj * 512);
                bl[nj] = *(const bf16x8*)(bb + (size_t)T * 32 + nj * 512);
            }
            const int rot = (ap + fro) & 7;
            bf16x8 ah[4], al[4];
#pragma unroll
            for (int mi = 0; mi < 4; ++mi) {
                const int ad = ibase + mi * 512 + rot * 8;
                ah[mi] = *(const bf16x8*)&Ih[ibuf][ad];
                al[mi] = *(const bf16x8*)&Il[ibuf][ad];
            }
            __builtin_amdgcn_s_setprio(1);
#pragma unroll
            for (int mi = 0; mi < 4; ++mi)
#pragma unroll
                for (int nj = 0; nj < 4; ++nj) {
                    acc[mi][nj] = __builtin_amdgcn_mfma_f32_16x16x32_bf16(ah[mi], bh[nj], acc[mi][nj], 0, 0, 0);
                    acc[mi][nj] = __builtin_amdgcn_mfma_f32_16x16x32_bf16(ah[mi], bl[nj], acc[mi][nj], 0, 0, 0);
                    acc[mi][nj] = __builtin_amdgcn_mfma_f32_16x16x32_bf16(al[mi], bh[nj], acc[mi][nj], 0, 0, 0);
                }
            __builtin_amdgcn_s_setprio(0);
            // ---- interleaved I-build task for this ap ----
            if (hn && ap >= 2) {
                const int task = ap - 2;
                if (task < NI) {
                    if (CROW == 128) {
                        float4 a4 = qr0[task], b4 = qr1[task], c4 = qr2[task];
                        vv[task * 4 + 0] = nw0 * a4.x + nw1 * b4.x + nw2 * c4.x;
                        vv[task * 4 + 1] = nw0 * a4.y + nw1 * b4.y + nw2 * c4.y;
                        vv[task * 4 + 2] = nw0 * a4.z + nw1 * b4.z + nw2 * c4.z;
                        vv[task * 4 + 3] = nw0 * a4.w + nw1 * b4.w + nw2 * c4.w;
                    } else {
#pragma unroll
                        for (int j = 0; j < 4; ++j)
                            vv[task * 4 + j] = nw0 * gq0[task * 4 + j] + nw1 * gq1[task * 4 + j] + nw2 * gq2[task * 4 + j];
                    }
                } else if (task < NI + NSW) {
                    split_write_half(vv, task - NI, (gidx + 1) & 1);
                }
            }
        }
        __syncthreads();
    }

    if (FUSE) {
        // elu + bias, per-row squared norms, argmax over 8 rotations, BN
        float ss[4][4];
#pragma unroll
        for (int mi = 0; mi < 4; ++mi)
#pragma unroll
            for (int r = 0; r < 4; ++r) ss[mi][r] = 0.f;
#pragma unroll
        for (int mi = 0; mi < 4; ++mi)
#pragma unroll
            for (int nj = 0; nj < 4; ++nj)
#pragma unroll
                for (int r = 0; r < 4; ++r) {
                    float val = elu_f(acc[mi][nj][r] + bias[wn + nj * 16 + fr]);
                    acc[mi][nj][r] = val;
                    ss[mi][r] += val * val;
                }
#pragma unroll
        for (int mi = 0; mi < 4; ++mi)
#pragma unroll
            for (int r = 0; r < 4; ++r) {
                float s = ss[mi][r];
                s += __shfl_xor(s, 1); s += __shfl_xor(s, 2);
                s += __shfl_xor(s, 4); s += __shfl_xor(s, 8);
                if (fr == 0) normp[mi * 16 + fq * 4 + r][wid] = s;
            }
        __syncthreads();
        if (POOL) poolmax[tid] = 0u;
        if (tid < 8) {
            float best = -1.f; int bsel = 0;
#pragma unroll
            for (int oo = 0; oo < 8; ++oo) {
                float tot = 0.f;
#pragma unroll
                for (int wq = 0; wq < NW; ++wq) tot += normp[tid * 8 + oo][wq];
                if (tot > best) { best = tot; bsel = oo; }   // first max wins
            }
            bo[tid] = bsel;
        }
        __syncthreads();
        const float rsbn = rsqrtf(1.001f);
        if (!POOL) {
#pragma unroll
            for (int mi = 0; mi < 4; ++mi)
#pragma unroll
                for (int r = 0; r < 4; ++r) {
                    int row = mi * 16 + fq * 4 + r;
                    if ((row & 7) == bo[row >> 3]) {
                        int vg = (m0 >> 3) + (row >> 3);   // global vertex 0..8191
#pragma unroll
                        for (int nj = 0; nj < 4; ++nj) {
                            int t = wn + nj * 16 + fr;
                            xout[(size_t)vg * T + t] = acc[mi][nj][r] * g[t] * rsbn + be[t];
                        }
                    }
                }
        } else {
            // fused GlobalMaxPool: BN'd selected rows -> LDS uint max -> global
#pragma unroll
            for (int mi = 0; mi < 4; ++mi)
#pragma unroll
                for (int r = 0; r < 4; ++r) {
                    int row = mi * 16 + fq * 4 + r;
                    if ((row & 7) == bo[row >> 3]) {
#pragma unroll
                        for (int nj = 0; nj < 4; ++nj) {
                            int t = wn + nj * 16 + fr;
                            float f = acc[mi][nj][r] * g[t] * rsbn + be[t];
                            atomicMax(&poolmax[t], encf(f));
                        }
                    }
                }
            __syncthreads();
            unsigned pv = poolmax[tid];
            if (pv) atomicMax((unsigned*)xout + (((size_t)b) << 8) + tid, pv);
        }
    }
}

// Fused head: decode pooled max + 3-layer MLP. One block per batch.
__global__ __launch_bounds__(256) void head_k(const float* __restrict__ partial,
                                              const float* __restrict__ w1, const float* __restrict__ c1,
                                              const float* __restrict__ w2, const float* __restrict__ c2,
                                              const float* __restrict__ w3, const float* __restrict__ c3,
                                              float* __restrict__ outp) {
    __shared__ float p[256], h1s[512], h2s[256];
    const int b = blockIdx.x, tid = threadIdx.x;
    const unsigned* gp = (const unsigned*)partial;
    p[tid] = decf(gp[b * 256 + tid]);
    __syncthreads();
#pragma unroll
    for (int rep = 0; rep < 2; ++rep) {
        int n = rep * 256 + tid;
        float s = c1[n];
        for (int k = 0; k < 256; ++k) s += p[k] * w1[k * 512 + n];
        h1s[n] = elu_f(s);
    }
    __syncthreads();
    {
        float s = c2[tid];
        for (int k = 0; k < 512; ++k) s += h1s[k] * w2[k * 256 + tid];
        h2s[tid] = elu_f(s);
    }
    __syncthreads();
    if (tid < 40) {
        float s = c3[tid];
        for (int k = 0; k < 256; ++k) s += h2s[k] * w3[k * 40 + tid];
        outp[b * 40 + tid] = s;
    }
}

extern "C" void kernel_launch(void* const* d_in, const int* in_sizes, int n_in,
                              void* d_out, int out_size, void* d_ws, size_t ws_size,
                              hipStream_t stream) {
    const float* signal = (const float*)d_in[0];
    const int* bc_idx = (const int*)d_in[1];
    const float* bc_w = (const float*)d_in[2];
    const float* k0 = (const float*)d_in[3];
    const float* b0 = (const float*)d_in[4];
    const float* g0 = (const float*)d_in[5];
    const float* be0 = (const float*)d_in[6];
    const float* k1 = (const float*)d_in[7];
    const float* b1 = (const float*)d_in[8];
    const float* g1 = (const float*)d_in[9];
    const float* be1 = (const float*)d_in[10];
    const float* k2 = (const float*)d_in[11];
    const float* b2 = (const float*)d_in[12];
    const float* g2 = (const float*)d_in[13];
    const float* be2 = (const float*)d_in[14];
    const float* w1 = (const float*)d_in[15];
    const float* c1 = (const float*)d_in[16];
    const float* w2 = (const float*)d_in[17];
    const float* c2 = (const float*)d_in[18];
    const float* w3 = (const float*)d_in[19];
    const float* c3 = (const float*)d_in[20];
    float* outp = (float*)d_out;

    // Workspace layout (x buffers are [8192][128] f32 = 4MB each; total ~17MB):
    // xa 4MB | xb 4MB | gpool 4KB(+pad) | wt0 0.66MB | wt1 2.62MB | wt2 5.24MB
    float* ws = (float*)d_ws;
    float* xa = ws;                                        // [8192][<=128] f32
    float* xb = xa + (size_t)8192 * 128;
    unsigned* gpool = (unsigned*)(xb + (size_t)8192 * 128); // [4][256] enc-u32
    unsigned short* wt0 = (unsigned short*)(gpool + 4096);
    unsigned short* wt1 = wt0 + (size_t)40 * 2 * 128 * 32;
    unsigned short* wt2 = wt1 + (size_t)160 * 2 * 128 * 32;

    // 1. prep: norm -> xa, expand all three weight slabs, zero gpool
    prep_k<<<9284, 256, 0, stream>>>(signal, xa, k0, wt0, k1, wt1, k2, wt2, gpool);

    // ---- layer 0: CROW=30 (KB=40), T=128, NW=2 (128 thr, BM=64), fused AMP ----
    conv_k<30, 128, 40, 2, true, false><<<dim3(1, 1024), 128, 0, stream>>>(
        xa, bc_idx, bc_w, wt0, b0, g0, be0, xb);

    // ---- layer 1: CROW=128 (KB=160), T=128, NW=2 (128 thr, BM=64), fused AMP ----
    conv_k<128, 128, 160, 2, true, false><<<dim3(1, 1024), 128, 0, stream>>>(
        xb, bc_idx, bc_w, wt1, b1, g1, be1, xa);

    // ---- layer 2: CROW=128 (KB=160), T=256, NW=4 (256 thr, BM=64), fused AMP+POOL ----
    conv_k<128, 256, 160, 4, true, true><<<dim3(1, 1024), 256, 0, stream>>>(
        xa, bc_idx, bc_w, wt2, b2, g2, be2, (float*)gpool);

    // ---- fused MLP head (decodes pooled max) ----
    head_k<<<Bz, 256, 0, stream>>>((const float*)gpool, w1, c1, w2, c2, w3, c3, outp);
}

// Round 8
// 571.333 us; speedup vs baseline: 1.9956x; 1.3744x over previous
//
#include <hip/hip_runtime.h>
#include <hip/hip_bf16.h>
#include <math.h>

// Problem constants
#define Bz 4
#define Vz 2048
#define RA 40   // R*A = 5*8

typedef short bf16x8 __attribute__((ext_vector_type(8)));
typedef float f32x4 __attribute__((ext_vector_type(4)));

__device__ __forceinline__ unsigned fasu(float f){ union{float f;unsigned u;}x;x.f=f;return x.u; }
__device__ __forceinline__ float usaf(unsigned u){ union{unsigned u;float f;}x;x.u=u;return x.f; }

// fp32 -> bf16 RNE (weight split, done once per layer)
__device__ __forceinline__ unsigned short f2bf(float f) {
    unsigned u = fasu(f);
    unsigned r = u + 0x7FFF + ((u >> 16) & 1);
    return (unsigned short)(r >> 16);
}
__device__ __forceinline__ float bf2f(unsigned short h) { return usaf(((unsigned)h) << 16); }

__constant__ float NORM_MEAN_C[30] = {
    -3.7189561e-06f, 0.000286194f, 0.0020740835f, 6.5275993f, -0.0052857199f,
    10.554636f, 0.057773598f, 13.915789f, 0.060970016f, 16.840271f,
    0.0570364f, 19.415283f, 0.044104282f, 21.721455f, 0.11490919f,
    23.64683f, 0.099816084f, 25.365578f, 0.01769533f, 26.861437f,
    0.054662503f, 28.197876f, -0.0024771576f, 29.295244f, 0.039666731f,
    30.319246f, 0.0088442909f, 31.160933f, -0.026727753f, 31.874565f};
__constant__ float NORM_VAR_C[30] = {
    3.3091978e-06f, 0.00016750646f, 0.80988622f, 85135.219f, 1.5621265f,
    222580.2f, 8.812871f, 386912.78f, 10.180468f, 566622.44f,
    9.8600769f, 753158.06f, 7.8372045f, 942701.62f, 30.926426f,
    1117233.0f, 25.045353f, 1285543.9f, 6.3646226f, 1441639.1f,
    12.326629f, 1588653.4f, 6.9686499f, 1714707.9f, 10.755516f,
    1836677.8f, 8.416419f, 1940088.8f, 10.344138f, 2029969.6f};

__device__ __forceinline__ float elu_f(float x) {
    return x > 0.f ? x : expm1f(x);
}

// order-preserving float->uint map (uint max == float max, bit-exact)
__device__ __forceinline__ unsigned encf(float f) {
    unsigned u = fasu(f);
    return (f < 0.f) ? ~u : (u | 0x80000000u);
}
__device__ __forceinline__ float decf(unsigned u) {
    return (u & 0x80000000u) ? usaf(u & 0x7FFFFFFFu) : usaf(~u);
}

// Weight expand, parity-transformed: kb = ((r*CB + cblk)*4 + j)*2 + p,
// p=0 -> Ks[j]/2 = (K[r,j]+K[r,j+4])/2 ; p=1 -> Kd[j]/2 = (K[r,j]-K[r,j+4])/2.
// Split-bf16, fragment-linear within kb: off = (n>>4)*512 + (kk>>3)*128 +
// (n&15)*8 + (kk&7); lo plane at +T*32.
template <int CROW, int T, int KB>
__device__ __forceinline__ void expand_body(int e, const float* __restrict__ kern,
                                            unsigned short* __restrict__ wt) {
    constexpr int CB = (CROW == 128) ? 4 : 1;
    int kb = e / (T * 32);
    int rem = e % (T * 32);
    int n = rem >> 5, kk = rem & 31;
    int par = kb & 1;
    int jp = (kb >> 1) & 3;
    int g = kb >> 3;                 // = r*CB + cblk
    int cblk = g % CB;
    int r = g / CB;
    int c = cblk * 32 + kk;
    float v = 0.f;
    if (c < CROW) {
        float k1 = kern[((size_t)((r * 8 + jp) * T + n)) * CROW + c];
        float k2 = kern[((size_t)((r * 8 + jp + 4) * T + n)) * CROW + c];
        v = 0.5f * (par == 0 ? (k1 + k2) : (k1 - k2));
    }
    unsigned short hi = f2bf(v);
    unsigned short lo = f2bf(v - bf2f(hi));
    size_t off = ((size_t)kb * 2) * T * 32 + (n >> 4) * 512 + (kk >> 3) * 128 + (n & 15) * 8 + (kk & 7);
    wt[off] = hi;
    wt[off + (size_t)T * 32] = lo;
}

// One prep dispatch: norm + 3x expand + pool-buffer zero (region-dispatch).
__global__ void prep_k(const float* __restrict__ sig, float* __restrict__ x0,
                       const float* __restrict__ k0, unsigned short* __restrict__ wt0,
                       const float* __restrict__ k1, unsigned short* __restrict__ wt1,
                       const float* __restrict__ k2, unsigned short* __restrict__ wt2,
                       unsigned* __restrict__ gpool) {
    const int bid = blockIdx.x, tid = threadIdx.x;
    if (bid < 960) {
        int e = bid * 256 + tid;
        if (e < Bz * Vz * 30) {
            int c = e % 30;
            x0[e] = (sig[e] - NORM_MEAN_C[c]) * rsqrtf(NORM_VAR_C[c]);
        }
    } else if (bid < 1600) {
        int e = (bid - 960) * 256 + tid;
        if (e < 40 * 128 * 32) expand_body<30, 128, 40>(e, k0, wt0);
    } else if (bid < 4160) {
        int e = (bid - 1600) * 256 + tid;
        if (e < 160 * 128 * 32) expand_body<128, 128, 160>(e, k1, wt1);
    } else if (bid < 9280) {
        int e = (bid - 4160) * 256 + tid;
        if (e < 160 * 256 * 32) expand_body<128, 256, 160>(e, k2, wt2);
    } else {
        int e = (bid - 9280) * 256 + tid;
        if (e < Bz * 256) gpool[e] = 0u;
    }
}

// Fused conv GEMM, R7: radix-2 parity decomposition of the length-8 angular
// circular correlation. out[o]+out[o+4] = sum_j Ie[(j+o)&3]*Ks[j] (circular-4);
// out[o]-out[o+4] = sum_j IoExt[(j+o)&7]*Kd[j] (negacyclic-4 via antiperiodic
// doubled storage IoExt[s]=Io[s] s<4, -Io[s-4] s>=4). HALVES MFMA count:
// M-tile = 8v x {4 even rows + 4 odd rows}; each of the 8 steps/group (j x p)
// fires only its parity's 2 m-frags -> 192 MFMA/group vs 384. B traffic, group
// /barrier schedule (R3: one barrier/group, interleaved I-build tasks,
// s_setprio) unchanged. Weights carry the 1/2: wt = Ks/2, Kd/2; epilogue:
// out[o]=Se'+So', out[o+4]=Se'-So'. A-LDS: 16 slots/vertex (IeExt 8 + IoExt
// 8), slot swizzled by +2*(v&3) for bank spread. VGPR pinned <=128 (R4/R5
// lesson); ah/al halves (2 frags/step) which pays for the doubled idx regs.
// Sign-flip-by-XOR on split-bf16 planes is bit-exact (IEEE truncation is
// sign-symmetric, so hi(-v) = -hi(v) and lo(-v) = -lo(v)).
// Epilogue: elu+bias, AMP argmax over 8 rotations, BN, write or fused pool.
template <int CROW, int T, int KB, int NW, bool FUSE, bool POOL>
__global__ __launch_bounds__(64 * NW) void conv_k(const float* __restrict__ x,
                                              const int* __restrict__ bc_idx,
                                              const float* __restrict__ bc_w,
                                              const unsigned short* __restrict__ wt,
                                              const float* __restrict__ bias,
                                              const float* __restrict__ g,
                                              const float* __restrict__ be,
                                              float* __restrict__ xout) {
    constexpr int CB = (CROW == 128) ? 4 : 1;   // c-blocks per r
    constexpr int G = KB / 8;                   // (r,cblk) groups
    constexpr int CW = 2 * NW;                  // c-chunks per (v,j) build unit
    constexpr int CPT = 32 / CW;                // c-elements per thread (8 or 4)
    __shared__ unsigned short Ih[2][4096], Il[2][4096];
    __shared__ float normp[64][NW];
    __shared__ int bo[8];
    __shared__ unsigned poolmax[64 * NW];
    const int tid = threadIdx.x;
    const int wid = tid >> 6, lane = tid & 63;
    const int fr = lane & 15, fq = lane >> 4;
    const int fr2 = fr >> 2, om_l = fr & 3;
    const int wn = wid * 64;                      // column-wave offset
    const int m0 = blockIdx.y * 64;
    const int b = m0 >> 14;                       // batch
    const float* xb_ = x + (size_t)b * Vz * CROW;
    const int* idxb = bc_idx + (size_t)b * Vz * RA * 3;
    const float* wb = bc_w + (size_t)b * Vz * RA * 3;

    // I-build decomposition: thread = (vertex vbI, pair-index jI, c-chunk cidx)
    const int cidx = tid % CW;
    const int jI = (tid / CW) & 3;
    const int vbI = tid / (CW * 4);               // 0..7
    const int vglob_b = ((m0 & 16383) >> 3) + vbI;
    const int wbase = vbI * 512 + ((cidx * CPT) >> 3) * 128 + ((cidx * CPT) & 7);
    const int nbase = wn >> 4;

    f32x4 acc[4][4] = {};   // mi: 0,1 = even-part (vgrp 0,1); 2,3 = odd-part

    // pack split-bf16 and write to two slots (second optionally negated)
    auto store_split2 = [&](const float* vv, int buf, int sA, int sB, unsigned sgB) {
        unsigned hp[CPT / 2], lp[CPT / 2];
#pragma unroll
        for (int p2 = 0; p2 < CPT / 2; ++p2) {
            float v0 = vv[2 * p2], v1 = vv[2 * p2 + 1];
            unsigned u0 = fasu(v0), u1 = fasu(v1);
            unsigned h0 = u0 & 0xFFFF0000u, h1 = u1 & 0xFFFF0000u;
            float l0 = v0 - usaf(h0), l1 = v1 - usaf(h1);
            hp[p2] = (u0 >> 16) | h1;
            lp[p2] = (fasu(l0) >> 16) | (fasu(l1) & 0xFFFF0000u);
        }
        auto put = [&](int slot, unsigned sg) {
            const int sl = (slot & 8) | (((slot & 7) + 2 * (vbI & 3)) & 7);
            const int ad = wbase + sl * 8;
            if constexpr (CPT == 8) {
                *(uint4*)&Ih[buf][ad] = make_uint4(hp[0] ^ sg, hp[1] ^ sg, hp[2] ^ sg, hp[3] ^ sg);
                *(uint4*)&Il[buf][ad] = make_uint4(lp[0] ^ sg, lp[1] ^ sg, lp[2] ^ sg, lp[3] ^ sg);
            } else {
                *(uint2*)&Ih[buf][ad] = make_uint2(hp[0] ^ sg, hp[1] ^ sg);
                *(uint2*)&Il[buf][ad] = make_uint2(lp[0] ^ sg, lp[1] ^ sg);
            }
        };
        put(sA, 0u);
        put(sB, sgB);
    };

    // ---- prologue: build tile for group 0 (r=0,cblk=0); prefetch idx/w g=1 ----
    int i_n0 = 0, i_n1 = 0, i_n2 = 0, i_n3 = 0, i_n4 = 0, i_n5 = 0;
    float w_n0 = 0.f, w_n1 = 0.f, w_n2 = 0.f, w_n3 = 0.f, w_n4 = 0.f, w_n5 = 0.f;
    {
        const int gi1 = (vglob_b * RA + jI) * 3;
        const int gi2 = gi1 + 12;                 // (ra+4)*3
        int a0 = idxb[gi1], a1 = idxb[gi1 + 1], a2 = idxb[gi1 + 2];
        int a3 = idxb[gi2], a4 = idxb[gi2 + 1], a5 = idxb[gi2 + 2];
        float u0 = wb[gi1], u1 = wb[gi1 + 1], u2 = wb[gi1 + 2];
        float u3 = wb[gi2], u4 = wb[gi2 + 1], u5 = wb[gi2 + 2];
        float xj[CPT], xj4[CPT];
        const int cs0 = cidx * CPT;
        if (CROW == 128) {
            const float4* p0 = (const float4*)(xb_ + (size_t)a0 * CROW + cs0);
            const float4* p1 = (const float4*)(xb_ + (size_t)a1 * CROW + cs0);
            const float4* p2 = (const float4*)(xb_ + (size_t)a2 * CROW + cs0);
            const float4* p3 = (const float4*)(xb_ + (size_t)a3 * CROW + cs0);
            const float4* p4 = (const float4*)(xb_ + (size_t)a4 * CROW + cs0);
            const float4* p5 = (const float4*)(xb_ + (size_t)a5 * CROW + cs0);
#pragma unroll
            for (int qq = 0; qq < CPT / 4; ++qq) {
                float4 A = p0[qq], B = p1[qq], C = p2[qq];
                xj[qq * 4 + 0] = u0 * A.x + u1 * B.x + u2 * C.x;
                xj[qq * 4 + 1] = u0 * A.y + u1 * B.y + u2 * C.y;
                xj[qq * 4 + 2] = u0 * A.z + u1 * B.z + u2 * C.z;
                xj[qq * 4 + 3] = u0 * A.w + u1 * B.w + u2 * C.w;
                float4 D = p3[qq], E = p4[qq], F = p5[qq];
                xj4[qq * 4 + 0] = u3 * D.x + u4 * E.x + u5 * F.x;
                xj4[qq * 4 + 1] = u3 * D.y + u4 * E.y + u5 * F.y;
                xj4[qq * 4 + 2] = u3 * D.z + u4 * E.z + u5 * F.z;
                xj4[qq * 4 + 3] = u3 * D.w + u4 * E.w + u5 * F.w;
            }
        } else {
#pragma unroll
            for (int cc = 0; cc < CPT; ++cc) {
                int c = cs0 + cc;
                bool ok = (c < CROW);
                xj[cc] = ok ? (u0 * xb_[(size_t)a0 * CROW + c] + u1 * xb_[(size_t)a1 * CROW + c] + u2 * xb_[(size_t)a2 * CROW + c]) : 0.f;
                xj4[cc] = ok ? (u3 * xb_[(size_t)a3 * CROW + c] + u4 * xb_[(size_t)a4 * CROW + c] + u5 * xb_[(size_t)a5 * CROW + c]) : 0.f;
            }
        }
#pragma unroll
        for (int cc = 0; cc < CPT; ++cc) {
            float a_ = xj[cc], b_ = xj4[cc];
            xj[cc] = a_ + b_;                      // Ie
            xj4[cc] = a_ - b_;                     // Io
        }
        store_split2(xj, 0, jI, jI + 4, 0u);
        store_split2(xj4, 0, 8 + jI, 12 + jI, 0x80008000u);
        if (G > 1) {
            const int rn = 1 / CB;
            const int gi1n = (vglob_b * RA + rn * 8 + jI) * 3;
            const int gi2n = gi1n + 12;
            i_n0 = idxb[gi1n]; i_n1 = idxb[gi1n + 1]; i_n2 = idxb[gi1n + 2];
            i_n3 = idxb[gi2n]; i_n4 = idxb[gi2n + 1]; i_n5 = idxb[gi2n + 2];
            w_n0 = wb[gi1n]; w_n1 = wb[gi1n + 1]; w_n2 = wb[gi1n + 2];
            w_n3 = wb[gi2n]; w_n4 = wb[gi2n + 1]; w_n5 = wb[gi2n + 2];
        }
    }
    __syncthreads();

    for (int gidx = 0; gidx < G; ++gidx) {
        const bool hn = (gidx + 1 < G);
        // save idx/w for building group g+1 (prefetch for g+2 overwrites)
        const int ni0 = i_n0, ni1 = i_n1, ni2 = i_n2, ni3 = i_n3, ni4 = i_n4, ni5 = i_n5;
        const float mw0 = w_n0, mw1 = w_n1, mw2 = w_n2, mw3 = w_n3, mw4 = w_n4, mw5 = w_n5;
        const int bgn = gidx + 1;
        const int cs_n = (bgn % CB) * 32 + cidx * CPT;
        const int ibuf = gidx & 1;
        float4 qa0[CPT / 4], qa1[CPT / 4], qa2[CPT / 4];
        float4 qb0[CPT / 4], qb1[CPT / 4], qb2[CPT / 4];
        float sg[6][CPT];                          // CROW==30 scalar path
        float xj[CPT], xj4[CPT];
#pragma unroll
        for (int ap = 0; ap < 8; ++ap) {
            const int jp = ap >> 1, par = ap & 1;
            // ---- B fragment loads (Ks/2 for par=0, Kd/2 for par=1) ----
            const int kb = gidx * 8 + ap;
            const unsigned short* bb = wt + ((size_t)kb * 2) * (T * 32) +
                                       (size_t)nbase * 512 + lane * 8;
            bf16x8 bh[4], bl[4];
#pragma unroll
            for (int nj = 0; nj < 4; ++nj) {
                bh[nj] = *(const bf16x8*)(bb + nj * 512);
                bl[nj] = *(const bf16x8*)(bb + (size_t)T * 32 + nj * 512);
            }
            // ---- A fragments: slot (par, (jp+om)&7), swizzled; 2 m-frags ----
            const int sp = (jp + om_l + 2 * fr2) & 7;   // slot low3 after swizzle
            const int sl = par * 8 + sp;
            bf16x8 ah[2], al[2];
#pragma unroll
            for (int miq = 0; miq < 2; ++miq) {
                const int ad = (miq * 4 + fr2) * 512 + fq * 128 + sl * 8;
                ah[miq] = *(const bf16x8*)&Ih[ibuf][ad];
                al[miq] = *(const bf16x8*)&Il[ibuf][ad];
            }
            __builtin_amdgcn_s_setprio(1);
#pragma unroll
            for (int miq = 0; miq < 2; ++miq)
#pragma unroll
                for (int nj = 0; nj < 4; ++nj) {
                    const int mi = par * 2 + miq;
                    acc[mi][nj] = __builtin_amdgcn_mfma_f32_16x16x32_bf16(ah[miq], bh[nj], acc[mi][nj], 0, 0, 0);
                    acc[mi][nj] = __builtin_amdgcn_mfma_f32_16x16x32_bf16(ah[miq], bl[nj], acc[mi][nj], 0, 0, 0);
                    acc[mi][nj] = __builtin_amdgcn_mfma_f32_16x16x32_bf16(al[miq], bh[nj], acc[mi][nj], 0, 0, 0);
                }
            __builtin_amdgcn_s_setprio(0);
            // ---- interleaved I-build task for group g+1 ----
            if (hn) {
                if (ap == 0) {
                    if (CROW == 128) {
                        const float4* p0 = (const float4*)(xb_ + (size_t)ni0 * CROW + cs_n);
                        const float4* p1 = (const float4*)(xb_ + (size_t)ni1 * CROW + cs_n);
                        const float4* p2 = (const float4*)(xb_ + (size_t)ni2 * CROW + cs_n);
#pragma unroll
                        for (int qq = 0; qq < CPT / 4; ++qq) { qa0[qq] = p0[qq]; qa1[qq] = p1[qq]; qa2[qq] = p2[qq]; }
                    } else {
#pragma unroll
                        for (int cc = 0; cc < CPT; ++cc) {
                            int c = cs_n + cc;
                            bool ok = (c < CROW);
                            sg[0][cc] = ok ? xb_[(size_t)ni0 * CROW + c] : 0.f;
                            sg[1][cc] = ok ? xb_[(size_t)ni1 * CROW + c] : 0.f;
                            sg[2][cc] = ok ? xb_[(size_t)ni2 * CROW + c] : 0.f;
                        }
                    }
                } else if (ap == 1) {
                    if (CROW == 128) {
                        const float4* p3 = (const float4*)(xb_ + (size_t)ni3 * CROW + cs_n);
                        const float4* p4 = (const float4*)(xb_ + (size_t)ni4 * CROW + cs_n);
                        const float4* p5 = (const float4*)(xb_ + (size_t)ni5 * CROW + cs_n);
#pragma unroll
                        for (int qq = 0; qq < CPT / 4; ++qq) { qb0[qq] = p3[qq]; qb1[qq] = p4[qq]; qb2[qq] = p5[qq]; }
                    } else {
#pragma unroll
                        for (int cc = 0; cc < CPT; ++cc) {
                            int c = cs_n + cc;
                            bool ok = (c < CROW);
                            sg[3][cc] = ok ? xb_[(size_t)ni3 * CROW + c] : 0.f;
                            sg[4][cc] = ok ? xb_[(size_t)ni4 * CROW + c] : 0.f;
                            sg[5][cc] = ok ? xb_[(size_t)ni5 * CROW + c] : 0.f;
                        }
                    }
                } else if (ap == 2) {
                    if (gidx + 2 < G) {
                        const int rn = (gidx + 2) / CB;
                        const int gi1 = (vglob_b * RA + rn * 8 + jI) * 3;
                        const int gi2 = gi1 + 12;
                        i_n0 = idxb[gi1]; i_n1 = idxb[gi1 + 1]; i_n2 = idxb[gi1 + 2];
                        i_n3 = idxb[gi2]; i_n4 = idxb[gi2 + 1]; i_n5 = idxb[gi2 + 2];
                        w_n0 = wb[gi1]; w_n1 = wb[gi1 + 1]; w_n2 = wb[gi1 + 2];
                        w_n3 = wb[gi2]; w_n4 = wb[gi2 + 1]; w_n5 = wb[gi2 + 2];
                    }
                } else if (ap == 3) {
                    if (CROW == 128) {
#pragma unroll
                        for (int qq = 0; qq < CPT / 4; ++qq) {
                            float4 A = qa0[qq], B = qa1[qq], C = qa2[qq];
                            xj[qq * 4 + 0] = mw0 * A.x + mw1 * B.x + mw2 * C.x;
                            xj[qq * 4 + 1] = mw0 * A.y + mw1 * B.y + mw2 * C.y;
                            xj[qq * 4 + 2] = mw0 * A.z + mw1 * B.z + mw2 * C.z;
                            xj[qq * 4 + 3] = mw0 * A.w + mw1 * B.w + mw2 * C.w;
                        }
                    } else {
#pragma unroll
                        for (int cc = 0; cc < CPT; ++cc)
                            xj[cc] = mw0 * sg[0][cc] + mw1 * sg[1][cc] + mw2 * sg[2][cc];
                    }
                } else if (ap == 4) {
                    if (CROW == 128) {
#pragma unroll
                        for (int qq = 0; qq < CPT / 4; ++qq) {
                            float4 D = qb0[qq], E = qb1[qq], F = qb2[qq];
                            xj4[qq * 4 + 0] = mw3 * D.x + mw4 * E.x + mw5 * F.x;
                            xj4[qq * 4 + 1] = mw3 * D.y + mw4 * E.y + mw5 * F.y;
                            xj4[qq * 4 + 2] = mw3 * D.z + mw4 * E.z + mw5 * F.z;
                            xj4[qq * 4 + 3] = mw3 * D.w + mw4 * E.w + mw5 * F.w;
                        }
                    } else {
#pragma unroll
                        for (int cc = 0; cc < CPT; ++cc)
                            xj4[cc] = mw3 * sg[3][cc] + mw4 * sg[4][cc] + mw5 * sg[5][cc];
                    }
                } else if (ap == 5) {
#pragma unroll
                    for (int cc = 0; cc < CPT; ++cc) {
                        float a_ = xj[cc], b_ = xj4[cc];
                        xj[cc] = a_ + b_;          // Ie
                        xj4[cc] = a_ - b_;         // Io
                    }
                } else if (ap == 6) {
                    store_split2(xj, ibuf ^ 1, jI, jI + 4, 0u);
                } else {
                    store_split2(xj4, ibuf ^ 1, 8 + jI, 12 + jI, 0x80008000u);
                }
            }
        }
        __syncthreads();
    }

    if (FUSE) {
        // reconstruct out[o]=Se'+So', out[o+4]=Se'-So'; elu+bias; AMP; BN
        float ssP[2][4], ssM[2][4];
#pragma unroll
        for (int mg = 0; mg < 2; ++mg)
#pragma unroll
            for (int r = 0; r < 4; ++r) { ssP[mg][r] = 0.f; ssM[mg][r] = 0.f; }
#pragma unroll
        for (int mg = 0; mg < 2; ++mg)
#pragma unroll
            for (int nj = 0; nj < 4; ++nj)
#pragma unroll
                for (int r = 0; r < 4; ++r) {
                    const int t = wn + nj * 16 + fr;
                    float se = acc[mg][nj][r], so = acc[mg + 2][nj][r];
                    float vP = elu_f(se + so + bias[t]);   // o = r
                    float vM = elu_f(se - so + bias[t]);   // o = r+4
                    acc[mg][nj][r] = vP;
                    acc[mg + 2][nj][r] = vM;
                    ssP[mg][r] += vP * vP;
                    ssM[mg][r] += vM * vM;
                }
#pragma unroll
        for (int mg = 0; mg < 2; ++mg)
#pragma unroll
            for (int r = 0; r < 4; ++r) {
                float s1 = ssP[mg][r];
                s1 += __shfl_xor(s1, 1); s1 += __shfl_xor(s1, 2);
                s1 += __shfl_xor(s1, 4); s1 += __shfl_xor(s1, 8);
                float s2 = ssM[mg][r];
                s2 += __shfl_xor(s2, 1); s2 += __shfl_xor(s2, 2);
                s2 += __shfl_xor(s2, 4); s2 += __shfl_xor(s2, 8);
                if (fr == 0) {
                    normp[(mg * 4 + fq) * 8 + r][wid] = s1;
                    normp[(mg * 4 + fq) * 8 + r + 4][wid] = s2;
                }
            }
        __syncthreads();
        if (POOL) poolmax[tid] = 0u;
        if (tid < 8) {
            float best = -1.f; int bsel = 0;
#pragma unroll
            for (int oo = 0; oo < 8; ++oo) {
                float tot = 0.f;
#pragma unroll
                for (int wq = 0; wq < NW; ++wq) tot += normp[tid * 8 + oo][wq];
                if (tot > best) { best = tot; bsel = oo; }   // first max wins
            }
            bo[tid] = bsel;
        }
        __syncthreads();
        const float rsbn = rsqrtf(1.001f);
#pragma unroll
        for (int mg = 0; mg < 2; ++mg)
#pragma unroll
            for (int r = 0; r < 4; ++r) {
                const int vloc = mg * 4 + fq;
                const int bsel = bo[vloc];
                if (r == bsel) {
                    const int vg = (m0 >> 3) + vloc;
#pragma unroll
                    for (int nj = 0; nj < 4; ++nj) {
                        const int t = wn + nj * 16 + fr;
                        float f = acc[mg][nj][r] * g[t] * rsbn + be[t];
                        if (!POOL) xout[(size_t)vg * T + t] = f;
                        else atomicMax(&poolmax[t], encf(f));
                    }
                }
                if (r + 4 == bsel) {
                    const int vg = (m0 >> 3) + vloc;
#pragma unroll
                    for (int nj = 0; nj < 4; ++nj) {
                        const int t = wn + nj * 16 + fr;
                        float f = acc[mg + 2][nj][r] * g[t] * rsbn + be[t];
                        if (!POOL) xout[(size_t)vg * T + t] = f;
                        else atomicMax(&poolmax[t], encf(f));
                    }
                }
            }
        if (POOL) {
            __syncthreads();
            unsigned pv = poolmax[tid];
            if (pv) atomicMax((unsigned*)xout + (((size_t)b) << 8) + tid, pv);
        }
    }
}

// Fused head: decode pooled max + 3-layer MLP. One block per batch.
__global__ __launch_bounds__(256) void head_k(const float* __restrict__ partial,
                                              const float* __restrict__ w1, const float* __restrict__ c1,
                                              const float* __restrict__ w2, const float* __restrict__ c2,
                                              const float* __restrict__ w3, const float* __restrict__ c3,
                                              float* __restrict__ outp) {
    __shared__ float p[256], h1s[512], h2s[256];
    const int b = blockIdx.x, tid = threadIdx.x;
    const unsigned* gp = (const unsigned*)partial;
    p[tid] = decf(gp[b * 256 + tid]);
    __syncthreads();
#pragma unroll
    for (int rep = 0; rep < 2; ++rep) {
        int n = rep * 256 + tid;
        float s = c1[n];
        for (int k = 0; k < 256; ++k) s += p[k] * w1[k * 512 + n];
        h1s[n] = elu_f(s);
    }
    __syncthreads();
    {
        float s = c2[tid];
        for (int k = 0; k < 512; ++k) s += h1s[k] * w2[k * 256 + tid];
        h2s[tid] = elu_f(s);
    }
    __syncthreads();
    if (tid < 40) {
        float s = c3[tid];
        for (int k = 0; k < 256; ++k) s += h2s[k] * w3[k * 40 + tid];
        outp[b * 40 + tid] = s;
    }
}

extern "C" void kernel_launch(void* const* d_in, const int* in_sizes, int n_in,
                              void* d_out, int out_size, void* d_ws, size_t ws_size,
                              hipStream_t stream) {
    const float* signal = (const float*)d_in[0];
    const int* bc_idx = (const int*)d_in[1];
    const float* bc_w = (const float*)d_in[2];
    const float* k0 = (const float*)d_in[3];
    const float* b0 = (const float*)d_in[4];
    const float* g0 = (const float*)d_in[5];
    const float* be0 = (const float*)d_in[6];
    const float* k1 = (const float*)d_in[7];
    const float* b1 = (const float*)d_in[8];
    const float* g1 = (const float*)d_in[9];
    const float* be1 = (const float*)d_in[10];
    const float* k2 = (const float*)d_in[11];
    const float* b2 = (const float*)d_in[12];
    const float* g2 = (const float*)d_in[13];
    const float* be2 = (const float*)d_in[14];
    const float* w1 = (const float*)d_in[15];
    const float* c1 = (const float*)d_in[16];
    const float* w2 = (const float*)d_in[17];
    const float* c2 = (const float*)d_in[18];
    const float* w3 = (const float*)d_in[19];
    const float* c3 = (const float*)d_in[20];
    float* outp = (float*)d_out;

    // Workspace layout: xa 4MB | xb 4MB | gpool 16KB | wt0 0.66MB | wt1 2.62MB | wt2 5.24MB
    float* ws = (float*)d_ws;
    float* xa = ws;                                        // [8192][<=128] f32
    float* xb = xa + (size_t)8192 * 128;
    unsigned* gpool = (unsigned*)(xb + (size_t)8192 * 128); // [4][256] enc-u32
    unsigned short* wt0 = (unsigned short*)(gpool + 4096);
    unsigned short* wt1 = wt0 + (size_t)40 * 2 * 128 * 32;
    unsigned short* wt2 = wt1 + (size_t)160 * 2 * 128 * 32;

    // 1. prep: norm -> xa, expand (parity-transformed) weights, zero gpool
    prep_k<<<9284, 256, 0, stream>>>(signal, xa, k0, wt0, k1, wt1, k2, wt2, gpool);

    // ---- layer 0: CROW=30 (KB=40), T=128, NW=2 (128 thr, BM=64), fused AMP ----
    conv_k<30, 128, 40, 2, true, false><<<dim3(1, 1024), 128, 0, stream>>>(
        xa, bc_idx, bc_w, wt0, b0, g0, be0, xb);

    // ---- layer 1: CROW=128 (KB=160), T=128, NW=2 (128 thr, BM=64), fused AMP ----
    conv_k<128, 128, 160, 2, true, false><<<dim3(1, 1024), 128, 0, stream>>>(
        xb, bc_idx, bc_w, wt1, b1, g1, be1, xa);

    // ---- layer 2: CROW=128 (KB=160), T=256, NW=4 (256 thr, BM=64), fused AMP+POOL ----
    conv_k<128, 256, 160, 4, true, true><<<dim3(1, 1024), 256, 0, stream>>>(
        xa, bc_idx, bc_w, wt2, b2, g2, be2, (float*)gpool);

    // ---- fused MLP head (decodes pooled max) ----
    head_k<<<Bz, 256, 0, stream>>>((const float*)gpool, w1, c1, w2, c2, w3, c3, outp);
}